// Round 1
// 1221.995 us; speedup vs baseline: 1.1014x; 1.1014x over previous
//
#include <hip/hip_runtime.h>

#define F_IN 512
#define C_DIM 64
#define BUCKET_BITS 9          // 512 nodes per bucket
#define EPB 2048               // edges per block in bucket_scatter

typedef __bf16 bf16x8 __attribute__((ext_vector_type(8)));
typedef float f32x4 __attribute__((ext_vector_type(4)));

__device__ inline unsigned bf_rne(float x) {      // fp32 -> bf16 bits (RNE)
    unsigned u = __float_as_uint(x);
    u += 0x7fffu + ((u >> 16) & 1u);
    return u >> 16;
}
__device__ inline unsigned bfpack(float x, float y) {
    return bf_rne(x) | (bf_rne(y) << 16);
}
__device__ inline bf16x8 as_bf16x8(uint4 u) {
    bf16x8 v; __builtin_memcpy(&v, &u, 16); return v;
}

// ---------------- degree histogram (int4 reads) ----------------
__global__ void deg_kernel(const int* __restrict__ col, int* __restrict__ deg, int E) {
    int i = blockIdx.x * blockDim.x + threadIdx.x;
    int e = i * 4;
    if (e + 3 < E) {
        int4 c4 = *(const int4*)(col + e);
        atomicAdd(&deg[c4.x], 1);
        atomicAdd(&deg[c4.y], 1);
        atomicAdd(&deg[c4.z], 1);
        atomicAdd(&deg[c4.w], 1);
    } else if (e < E) {
        for (int j = e; j < E; ++j) atomicAdd(&deg[col[j]], 1);
    }
}

// ---------------- dinv ----------------
__global__ void dinv_kernel(const int* __restrict__ deg, float* __restrict__ dinv, int N) {
    int i = blockIdx.x * blockDim.x + threadIdx.x;
    if (i < N) {
        int d = deg[i];
        dinv[i] = (d > 0) ? (1.0f / sqrtf((float)d)) : 1.0f;
    }
}

// ---------------- scan (3 kernels) ----------------
__global__ void scan1(const int* __restrict__ deg, int* __restrict__ rowptr,
                      int* __restrict__ bsum, int N) {
    __shared__ int tmp[1024];
    int t = threadIdx.x;
    int gid = blockIdx.x * 1024 + t;
    int v = (gid < N) ? deg[gid] : 0;
    tmp[t] = v;
    __syncthreads();
    for (int off = 1; off < 1024; off <<= 1) {
        int u = (t >= off) ? tmp[t - off] : 0;
        __syncthreads();
        tmp[t] += u;
        __syncthreads();
    }
    if (gid < N) rowptr[gid] = tmp[t] - v;
    if (t == 1023) bsum[blockIdx.x] = tmp[1023];
}

__global__ void scan2(int* __restrict__ bs, int nb) {
    __shared__ int tmp[1024];
    int t = threadIdx.x;
    int v = (t < nb) ? bs[t] : 0;
    tmp[t] = v;
    __syncthreads();
    for (int off = 1; off < 1024; off <<= 1) {
        int u = (t >= off) ? tmp[t - off] : 0;
        __syncthreads();
        tmp[t] += u;
        __syncthreads();
    }
    if (t < nb) bs[t] = tmp[t] - v;
}

__global__ void scan3(int* __restrict__ rowptr, const int* __restrict__ bs, int E, int N) {
    int gid = blockIdx.x * 1024 + threadIdx.x;
    if (gid < N) rowptr[gid] += bs[blockIdx.x];
    if (gid == 0) rowptr[N] = E;
}

// ---------------- bucket pointers ----------------
__global__ void bucketptr_kernel(const int* __restrict__ rowptr, int* __restrict__ bucketptr,
                                 int N, int NB) {
    int b = blockIdx.x * blockDim.x + threadIdx.x;
    if (b <= NB) {
        int idx = b << BUCKET_BITS;
        if (idx > N) idx = N;
        bucketptr[b] = rowptr[idx];
    }
}

// ---------------- pass B: bucket-grouped compact append ----------------
__global__ void bucket_scatter(const int* __restrict__ row, const int* __restrict__ col,
                               const float* __restrict__ dinv,
                               const int* __restrict__ bucketptr, int* __restrict__ bcnt,
                               int2* __restrict__ staged, int* __restrict__ staged_dst, int E) {
    __shared__ int lcnt[256];
    __shared__ int lbase[256];
    int t = threadIdx.x;
    lcnt[t] = 0;
    __syncthreads();
    int base_e = blockIdx.x * EPB;
    int rr[8], cc[8], pk[8];
    #pragma unroll
    for (int j = 0; j < 8; ++j) {
        int e = base_e + j * 256 + t;
        pk[j] = -1;
        if (e < E) {
            rr[j] = row[e];
            cc[j] = col[e];
            int b = cc[j] >> BUCKET_BITS;
            int off = atomicAdd(&lcnt[b], 1);
            pk[j] = off | (b << 20);
        }
    }
    __syncthreads();
    lbase[t] = atomicAdd(&bcnt[t], lcnt[t]);
    __syncthreads();
    #pragma unroll
    for (int j = 0; j < 8; ++j) {
        if (pk[j] >= 0) {
            int b = pk[j] >> 20;
            int off = pk[j] & 0xFFFFF;
            int pos = bucketptr[b] + lbase[b] + off;
            staged[pos] = make_int2(rr[j], __float_as_int(dinv[rr[j]] * dinv[cc[j]]));
            staged_dst[pos] = cc[j];
        }
    }
}

// ---------------- pass C: final in-bucket scatter ----------------
__global__ void final_scatter(const int2* __restrict__ staged, const int* __restrict__ staged_dst,
                              const int* __restrict__ rowptr, int* __restrict__ cnt,
                              int2* __restrict__ edges, int E) {
    int i = blockIdx.x * blockDim.x + threadIdx.x;
    if (i >= E) return;
    int c = staged_dst[i];
    int pos = rowptr[c] + atomicAdd(&cnt[c], 1);
    edges[pos] = staged[i];
}

// ---------------- W prepack: fp32 W -> (hi,lo) bf16 B-fragments ----------------
// layout: [kslot(16)][ct(4)][lane(64)] -> uint4 (8 bf16, j = k offset)
// lane -> col = ct*16 + (l&15), k = kslot*32 + 8*(l>>4) + j
__global__ void wprep_kernel(const float* __restrict__ W,
                             uint4* __restrict__ whi, uint4* __restrict__ wlo) {
    int tid = blockIdx.x * 256 + threadIdx.x;       // 4096 total
    int kslot = tid >> 8;
    int rem = tid & 255;
    int ct = rem >> 6;
    int l = rem & 63;
    int col = ct * 16 + (l & 15);
    int kbase = kslot * 32 + ((l >> 4) << 3);
    unsigned hbits[8], lbits[8];
    #pragma unroll
    for (int j = 0; j < 8; ++j) {
        float f = W[(size_t)(kbase + j) * C_DIM + col];
        unsigned h = bf_rne(f);
        hbits[j] = h;
        lbits[j] = bf_rne(f - __uint_as_float(h << 16));
    }
    whi[tid] = make_uint4(hbits[0] | (hbits[1] << 16), hbits[2] | (hbits[3] << 16),
                          hbits[4] | (hbits[5] << 16), hbits[6] | (hbits[7] << 16));
    wlo[tid] = make_uint4(lbits[0] | (lbits[1] << 16), lbits[2] | (lbits[3] << 16),
                          lbits[4] | (lbits[5] << 16), lbits[6] | (lbits[7] << 16));
}

// ---------------- split-bf16 MFMA GEMM: h = x @ W + b, emits bf16 hb directly ----
// block = 256 thr (4 waves), tile 128 rows x 64 cols, BK=64, 8 K-chunks.
// error vs fp32: ~2^-18 relative (lo*lo term dropped).
__global__ __launch_bounds__(256) void gemm_mfma(const float4* __restrict__ x4,
                                                 const uint4* __restrict__ whi,
                                                 const uint4* __restrict__ wlo,
                                                 const float* __restrict__ bias,
                                                 uint4* __restrict__ hb, int N) {
    __shared__ float smem[8704];          // 34816 B: staging (32K) / epilogue (34.8K)
    char* ahi = (char*)smem;
    char* alo = ahi + 16384;
    const int t = threadIdx.x;
    const int l = t & 63;
    const int wv = t >> 6;
    const int rowblk = blockIdx.x * 128;

    f32x4 acc[2][4];
    #pragma unroll
    for (int rt = 0; rt < 2; ++rt)
        #pragma unroll
        for (int ct = 0; ct < 4; ++ct) acc[rt][ct] = (f32x4){0.f, 0.f, 0.f, 0.f};

    for (int chunk = 0; chunk < 8; ++chunk) {
        // ---- stage A chunk: fp32 -> (hi,lo) bf16, XOR-swizzled 16B granules ----
        #pragma unroll
        for (int i = 0; i < 4; ++i) {
            int idx = t + 256 * i;            // 1024 granules: 128 rows x 8
            int r = idx >> 3, g = idx & 7;
            int grow = rowblk + r;
            float4 v0 = make_float4(0.f, 0.f, 0.f, 0.f), v1 = v0;
            if (grow < N) {
                const float4* p = x4 + (size_t)grow * (F_IN / 4) + chunk * 16 + g * 2;
                v0 = p[0]; v1 = p[1];
            }
            float f[8] = {v0.x, v0.y, v0.z, v0.w, v1.x, v1.y, v1.z, v1.w};
            unsigned hbits[8], lbits[8];
            #pragma unroll
            for (int j = 0; j < 8; ++j) {
                unsigned h = bf_rne(f[j]);
                hbits[j] = h;
                lbits[j] = bf_rne(f[j] - __uint_as_float(h << 16));
            }
            int off = r * 128 + ((g ^ (r & 7)) << 4);
            *(uint4*)(ahi + off) = make_uint4(hbits[0] | (hbits[1] << 16), hbits[2] | (hbits[3] << 16),
                                              hbits[4] | (hbits[5] << 16), hbits[6] | (hbits[7] << 16));
            *(uint4*)(alo + off) = make_uint4(lbits[0] | (lbits[1] << 16), lbits[2] | (lbits[3] << 16),
                                              lbits[4] | (lbits[5] << 16), lbits[6] | (lbits[7] << 16));
        }
        __syncthreads();
        // ---- A fragments (ds_read_b128, swizzle-matched) ----
        uint4 AH[2][2], AL[2][2];
        #pragma unroll
        for (int rt = 0; rt < 2; ++rt) {
            int r = wv * 32 + rt * 16 + (l & 15);
            int rb = r * 128;
            int rx = r & 7;
            #pragma unroll
            for (int ks = 0; ks < 2; ++ks) {
                int gl = ks * 4 + (l >> 4);
                int off = rb + ((gl ^ rx) << 4);
                AH[rt][ks] = *(const uint4*)(ahi + off);
                AL[rt][ks] = *(const uint4*)(alo + off);
            }
        }
        // ---- B fragments from global (L2-resident, 128 KB) + MFMA ----
        #pragma unroll
        for (int ct = 0; ct < 4; ++ct) {
            int base = (chunk * 8 + ct) * 64 + l;
            uint4 BH0 = whi[base], BH1 = whi[base + 256];
            uint4 BL0 = wlo[base], BL1 = wlo[base + 256];
            #pragma unroll
            for (int rt = 0; rt < 2; ++rt) {
                f32x4 c = acc[rt][ct];
                c = __builtin_amdgcn_mfma_f32_16x16x32_bf16(as_bf16x8(AH[rt][0]), as_bf16x8(BH0), c, 0, 0, 0);
                c = __builtin_amdgcn_mfma_f32_16x16x32_bf16(as_bf16x8(AH[rt][1]), as_bf16x8(BH1), c, 0, 0, 0);
                c = __builtin_amdgcn_mfma_f32_16x16x32_bf16(as_bf16x8(AL[rt][0]), as_bf16x8(BH0), c, 0, 0, 0);
                c = __builtin_amdgcn_mfma_f32_16x16x32_bf16(as_bf16x8(AL[rt][1]), as_bf16x8(BH1), c, 0, 0, 0);
                c = __builtin_amdgcn_mfma_f32_16x16x32_bf16(as_bf16x8(AH[rt][0]), as_bf16x8(BL0), c, 0, 0, 0);
                c = __builtin_amdgcn_mfma_f32_16x16x32_bf16(as_bf16x8(AH[rt][1]), as_bf16x8(BL1), c, 0, 0, 0);
                acc[rt][ct] = c;
            }
        }
        __syncthreads();
    }
    // ---- epilogue: acc -> LDS fp32 (transpose) -> packed bf16 hb ----
    float* ls = smem;                     // stride 68 dwords (16B-aligned rows)
    #pragma unroll
    for (int rt = 0; rt < 2; ++rt) {
        int rbase = wv * 32 + rt * 16 + ((l >> 4) << 2);
        #pragma unroll
        for (int ct = 0; ct < 4; ++ct) {
            int col = ct * 16 + (l & 15);
            float bb = bias[col];
            #pragma unroll
            for (int q = 0; q < 4; ++q)
                ls[(rbase + q) * 68 + col] = acc[rt][ct][q] + bb;
        }
    }
    __syncthreads();
    #pragma unroll
    for (int i = 0; i < 4; ++i) {
        int idx = t + 256 * i;
        int r = idx >> 3, lc = idx & 7;
        int grow = rowblk + r;
        if (grow < N) {
            const float* p = ls + r * 68 + lc * 8;
            float4 A = *(const float4*)p;
            float4 Bv = *(const float4*)(p + 4);
            uint4 nb;
            nb.x = bfpack(A.x, A.y);
            nb.y = bfpack(A.z, A.w);
            nb.z = bfpack(Bv.x, Bv.y);
            nb.w = bfpack(Bv.z, Bv.w);
            hb[(size_t)grow * 8 + lc] = nb;
        }
    }
}

// ---------------- propagation, bf16 state ----------------
// 8 lanes/node, each lane = 8 channels (one uint4 = 8 bf16).
// mode 0: Pout = prop(Hb);  mode 1: Pout = 2*prop(Hb) - unpack(Pold)
// ret == nullptr (lazy path): no ret accumulation; combine_kernel does it later.
__global__ void prop_kernel(const int* __restrict__ rowptr, const int2* __restrict__ edges,
                            const uint4* __restrict__ Hb, const uint4* Pold,
                            uint4* Pout, float4* ret, const float* lap,
                            const float4* mf4, int k, int mode, int N) {
    int gtid = blockIdx.x * blockDim.x + threadIdx.x;
    int node = gtid >> 3;
    int lc = gtid & 7;
    if (node >= N) return;
    int beg = rowptr[node];
    int end = rowptr[node + 1];
    float a0 = 0.f, a1 = 0.f, a2 = 0.f, a3 = 0.f, a4 = 0.f, a5 = 0.f, a6 = 0.f, a7 = 0.f;

#define EDGE_FMA(SRC, WB) do { \
        float w_ = __int_as_float(WB); \
        uint4 u_ = Hb[(size_t)(SRC) * 8 + lc]; \
        a0 = fmaf(w_, __uint_as_float(u_.x << 16), a0); \
        a1 = fmaf(w_, __uint_as_float(u_.x & 0xffff0000u), a1); \
        a2 = fmaf(w_, __uint_as_float(u_.y << 16), a2); \
        a3 = fmaf(w_, __uint_as_float(u_.y & 0xffff0000u), a3); \
        a4 = fmaf(w_, __uint_as_float(u_.z << 16), a4); \
        a5 = fmaf(w_, __uint_as_float(u_.z & 0xffff0000u), a5); \
        a6 = fmaf(w_, __uint_as_float(u_.w << 16), a6); \
        a7 = fmaf(w_, __uint_as_float(u_.w & 0xffff0000u), a7); \
    } while (0)

    int e = beg;
    if ((e & 1) && e < end) {
        int2 d = edges[e];
        EDGE_FMA(d.x, d.y);
        ++e;
    }
    for (; e + 4 <= end; e += 4) {
        int4 p0v = ((const int4*)edges)[e >> 1];
        int4 p1v = ((const int4*)edges)[(e >> 1) + 1];
        EDGE_FMA(p0v.x, p0v.y);
        EDGE_FMA(p0v.z, p0v.w);
        EDGE_FMA(p1v.x, p1v.y);
        EDGE_FMA(p1v.z, p1v.w);
    }
    for (; e < end; ++e) {
        int2 d = edges[e];
        EDGE_FMA(d.x, d.y);
    }
#undef EDGE_FMA

    size_t ib = (size_t)node * 8 + lc;
    float p0, p1, p2, p3, p4, p5, p6, p7;
    if (mode == 0) {
        p0 = a0; p1 = a1; p2 = a2; p3 = a3; p4 = a4; p5 = a5; p6 = a6; p7 = a7;
    } else {
        uint4 ob = Pold[ib];
        p0 = 2.f * a0 - __uint_as_float(ob.x << 16);
        p1 = 2.f * a1 - __uint_as_float(ob.x & 0xffff0000u);
        p2 = 2.f * a2 - __uint_as_float(ob.y << 16);
        p3 = 2.f * a3 - __uint_as_float(ob.y & 0xffff0000u);
        p4 = 2.f * a4 - __uint_as_float(ob.z << 16);
        p5 = 2.f * a5 - __uint_as_float(ob.z & 0xffff0000u);
        p6 = 2.f * a6 - __uint_as_float(ob.w << 16);
        p7 = 2.f * a7 - __uint_as_float(ob.w & 0xffff0000u);
    }
    uint4 nb;
    nb.x = bfpack(p0, p1);
    nb.y = bfpack(p2, p3);
    nb.z = bfpack(p4, p5);
    nb.w = bfpack(p6, p7);
    Pout[ib] = nb;

    if (ret) {   // legacy (small-workspace) path: accumulate into ret per iteration
        float lw = lap[k - 1];
        size_t i16 = (size_t)node * 16 + lc * 2;
        float4 m0 = mf4[k * 16 + lc * 2];
        float4 m1 = mf4[k * 16 + lc * 2 + 1];
        float4 r0 = ret[i16];
        float4 r1 = ret[i16 + 1];
        r0.x = fmaf(lw * m0.x, p0, r0.x);
        r0.y = fmaf(lw * m0.y, p1, r0.y);
        r0.z = fmaf(lw * m0.z, p2, r0.z);
        r0.w = fmaf(lw * m0.w, p3, r0.w);
        r1.x = fmaf(lw * m1.x, p4, r1.x);
        r1.y = fmaf(lw * m1.y, p5, r1.y);
        r1.z = fmaf(lw * m1.z, p6, r1.z);
        r1.w = fmaf(lw * m1.w, p7, r1.w);
        ret[i16] = r0;
        ret[i16 + 1] = r1;
    }
}

// ---------------- fused combine + log-softmax (lazy path) ----------------
// ret[n,c] = logsoftmax_c( h*mf0 + sum_k lap[k-1]*mf_k*P_k )
__global__ void combine_kernel(const uint4* __restrict__ hb, const uint4* __restrict__ Pall,
                               const float* __restrict__ lap, const float* __restrict__ mf,
                               float4* __restrict__ ret, int Kp, int N) {
    __shared__ float smf[1024];
    __shared__ float slap[32];
    int t = threadIdx.x;
    int nmf = (Kp + 1) * 64;
    for (int i = t; i < nmf; i += 256) smf[i] = mf[i];
    if (t < Kp) slap[t] = lap[t];
    __syncthreads();
    int g = blockIdx.x * 256 + t;
    int node = g >> 3, lc = g & 7;
    if (node >= N) return;
    size_t off = (size_t)node * 8 + lc;
    uint4 u = hb[off];
    const float* m0 = smf + lc * 8;
    float a0 = __uint_as_float(u.x << 16) * m0[0];
    float a1 = __uint_as_float(u.x & 0xffff0000u) * m0[1];
    float a2 = __uint_as_float(u.y << 16) * m0[2];
    float a3 = __uint_as_float(u.y & 0xffff0000u) * m0[3];
    float a4 = __uint_as_float(u.z << 16) * m0[4];
    float a5 = __uint_as_float(u.z & 0xffff0000u) * m0[5];
    float a6 = __uint_as_float(u.w << 16) * m0[6];
    float a7 = __uint_as_float(u.w & 0xffff0000u) * m0[7];
    size_t stride = (size_t)N * 8;
    for (int k = 1; k <= Kp; ++k) {
        uint4 p = Pall[(size_t)(k - 1) * stride + off];
        float cw = slap[k - 1];
        const float* mk = smf + k * 64 + lc * 8;
        a0 = fmaf(cw * mk[0], __uint_as_float(p.x << 16), a0);
        a1 = fmaf(cw * mk[1], __uint_as_float(p.x & 0xffff0000u), a1);
        a2 = fmaf(cw * mk[2], __uint_as_float(p.y << 16), a2);
        a3 = fmaf(cw * mk[3], __uint_as_float(p.y & 0xffff0000u), a3);
        a4 = fmaf(cw * mk[4], __uint_as_float(p.z << 16), a4);
        a5 = fmaf(cw * mk[5], __uint_as_float(p.z & 0xffff0000u), a5);
        a6 = fmaf(cw * mk[6], __uint_as_float(p.w << 16), a6);
        a7 = fmaf(cw * mk[7], __uint_as_float(p.w & 0xffff0000u), a7);
    }
    float m = fmaxf(fmaxf(fmaxf(a0, a1), fmaxf(a2, a3)), fmaxf(fmaxf(a4, a5), fmaxf(a6, a7)));
    for (int o = 1; o < 8; o <<= 1) m = fmaxf(m, __shfl_xor(m, o, 8));
    float s = __expf(a0 - m) + __expf(a1 - m) + __expf(a2 - m) + __expf(a3 - m)
            + __expf(a4 - m) + __expf(a5 - m) + __expf(a6 - m) + __expf(a7 - m);
    for (int o = 1; o < 8; o <<= 1) s += __shfl_xor(s, o, 8);
    float lg = logf(s) + m;
    ret[(size_t)node * 16 + lc * 2]     = make_float4(a0 - lg, a1 - lg, a2 - lg, a3 - lg);
    ret[(size_t)node * 16 + lc * 2 + 1] = make_float4(a4 - lg, a5 - lg, a6 - lg, a7 - lg);
}

// ---------------- legacy: init ret with P0 term ----------------
__global__ void p0ret_kernel(const uint4* __restrict__ hb, float4* __restrict__ ret,
                             const float4* __restrict__ mf4, int N) {
    int g = blockIdx.x * 256 + threadIdx.x;
    int node = g >> 3, lc = g & 7;
    if (node >= N) return;
    uint4 u = hb[(size_t)node * 8 + lc];
    float4 m0 = mf4[lc * 2], m1 = mf4[lc * 2 + 1];
    float4 r0 = make_float4(__uint_as_float(u.x << 16) * m0.x,
                            __uint_as_float(u.x & 0xffff0000u) * m0.y,
                            __uint_as_float(u.y << 16) * m0.z,
                            __uint_as_float(u.y & 0xffff0000u) * m0.w);
    float4 r1 = make_float4(__uint_as_float(u.z << 16) * m1.x,
                            __uint_as_float(u.z & 0xffff0000u) * m1.y,
                            __uint_as_float(u.w << 16) * m1.z,
                            __uint_as_float(u.w & 0xffff0000u) * m1.w);
    ret[(size_t)node * 16 + lc * 2] = r0;
    ret[(size_t)node * 16 + lc * 2 + 1] = r1;
}

// ---------------- log softmax (legacy path only) ----------------
__global__ void lsm_kernel(float* __restrict__ ret, int N) {
    int wid = (blockIdx.x * blockDim.x + threadIdx.x) >> 6;
    int c = threadIdx.x & 63;
    if (wid >= N) return;
    size_t idx = (size_t)wid * C_DIM + c;
    float v = ret[idx];
    float m = v;
    for (int off = 32; off; off >>= 1) m = fmaxf(m, __shfl_xor(m, off, 64));
    float ex = __expf(v - m);
    float s = ex;
    for (int off = 32; off; off >>= 1) s += __shfl_xor(s, off, 64);
    ret[idx] = (v - m) - logf(s);
}

extern "C" void kernel_launch(void* const* d_in, const int* in_sizes, int n_in,
                              void* d_out, int out_size, void* d_ws, size_t ws_size,
                              hipStream_t stream) {
    const float* x   = (const float*)d_in[0];
    const int*   ei  = (const int*)d_in[1];
    const float* W   = (const float*)d_in[2];
    const float* b   = (const float*)d_in[3];
    const float* lap = (const float*)d_in[4];
    const float* mf  = (const float*)d_in[5];
    float* ret = (float*)d_out;

    const int C = in_sizes[3];            // 64
    const int FIN = in_sizes[2] / C;      // 512
    const int N = in_sizes[0] / FIN;      // 100000
    const int E = in_sizes[1] / 2;        // 3200000
    const int K = in_sizes[4] - 1;        // 10
    const int* rowi = ei;
    const int* coli = ei + E;
    const int NB = (N + (1 << BUCKET_BITS) - 1) >> BUCKET_BITS;

    char* w = (char*)d_ws;
    auto alloc = [&](size_t bytes) {
        void* p = (void*)w;
        w += (bytes + 255) & ~(size_t)255;
        return p;
    };
    int*   deg    = (int*)alloc((size_t)N * 4);
    int*   cnt    = (int*)alloc((size_t)N * 4);
    int*   rowptr = (int*)alloc((size_t)(N + 1) * 4);
    int*   bsum   = (int*)alloc(4096);
    float* dinv   = (float*)alloc((size_t)N * 4);
    int*   bcnt   = (int*)alloc(1024);
    int*   bucketptr = (int*)alloc(4096);
    uint4* whi    = (uint4*)alloc(65536);                 // 16 kslot x 4 ct x 64 lane x 16B
    uint4* wlo    = (uint4*)alloc(65536);
    int2*  edges  = (int2*)alloc((size_t)E * 8);
    uint4* hb     = (uint4*)alloc((size_t)N * 128);       // bf16 h (P0), 12.8 MB

    const size_t slab = (size_t)N * 128;                  // one bf16 [N,64] buffer
    size_t used = (size_t)(w - (char*)d_ws);
    bool lazy = (ws_size > used) && ((ws_size - used) >= (size_t)K * slab);

    uint4* Pall = nullptr;
    uint4* pb = nullptr;
    int2* staged;
    int* staged_dst;
    if (lazy) {
        Pall = (uint4*)alloc((size_t)K * slab);           // P1..PK, 128 MB
        staged = (int2*)Pall;                             // dead until props start
        staged_dst = (int*)((char*)Pall + (size_t)E * 8);
    } else {
        pb = (uint4*)alloc(slab);
        staged = (int2*)hb;                               // hb+pb contiguous = E*8 bytes
        staged_dst = (int*)alloc((size_t)E * 4);
    }

    hipMemsetAsync(deg, 0, (size_t)N * 4, stream);
    hipMemsetAsync(cnt, 0, (size_t)N * 4, stream);
    hipMemsetAsync(bcnt, 0, 1024, stream);

    deg_kernel<<<((E + 3) / 4 + 255) / 256, 256, 0, stream>>>(coli, deg, E);
    dinv_kernel<<<(N + 255) / 256, 256, 0, stream>>>(deg, dinv, N);

    int nb = (N + 1023) / 1024;
    scan1<<<nb, 1024, 0, stream>>>(deg, rowptr, bsum, N);
    scan2<<<1, 1024, 0, stream>>>(bsum, nb);
    scan3<<<nb, 1024, 0, stream>>>(rowptr, bsum, E, N);
    bucketptr_kernel<<<(NB + 1 + 255) / 256, 256, 0, stream>>>(rowptr, bucketptr, N, NB);

    bucket_scatter<<<(E + EPB - 1) / EPB, 256, 0, stream>>>(rowi, coli, dinv, bucketptr,
                                                            bcnt, staged, staged_dst, E);
    final_scatter<<<(E + 255) / 256, 256, 0, stream>>>(staged, staged_dst, rowptr, cnt,
                                                       edges, E);

    wprep_kernel<<<16, 256, 0, stream>>>(W, whi, wlo);
    gemm_mfma<<<(N + 127) / 128, 256, 0, stream>>>((const float4*)x, whi, wlo, b, hb, N);

    int pgrid = (N * 8 + 255) / 256;
    if (lazy) {
        // P1 = prop(P0)
        prop_kernel<<<pgrid, 256, 0, stream>>>(rowptr, edges, hb, Pall, Pall,
                                               nullptr, nullptr, nullptr, 1, 0, N);
        for (int k2 = 2; k2 <= K; ++k2) {
            const uint4* src  = Pall + (size_t)(k2 - 2) * N * 8;
            const uint4* pold = (k2 == 2) ? hb : Pall + (size_t)(k2 - 3) * N * 8;
            uint4* out = Pall + (size_t)(k2 - 1) * N * 8;
            prop_kernel<<<pgrid, 256, 0, stream>>>(rowptr, edges, src, pold, out,
                                                   nullptr, nullptr, nullptr, k2, 1, N);
        }
        combine_kernel<<<pgrid, 256, 0, stream>>>(hb, Pall, lap, mf, (float4*)ret, K, N);
    } else {
        p0ret_kernel<<<pgrid, 256, 0, stream>>>(hb, (float4*)ret, (const float4*)mf, N);
        prop_kernel<<<pgrid, 256, 0, stream>>>(rowptr, edges, hb, pb, pb, (float4*)ret,
                                               lap, (const float4*)mf, 1, 0, N);
        uint4* gat = pb;
        uint4* st  = hb;
        for (int k2 = 2; k2 <= K; ++k2) {
            prop_kernel<<<pgrid, 256, 0, stream>>>(rowptr, edges, gat, st, st, (float4*)ret,
                                                   lap, (const float4*)mf, k2, 1, N);
            uint4* t2 = gat; gat = st; st = t2;
        }
        lsm_kernel<<<((size_t)N * 64 + 255) / 256, 256, 0, stream>>>(ret, N);
    }
}

// Round 2
// 1040.233 us; speedup vs baseline: 1.2939x; 1.1747x over previous
//
#include <hip/hip_runtime.h>

#define F_IN 512
#define C_DIM 64
#define BUCKET_BITS 9          // 512 nodes per bucket
#define EPB 2048               // edges per block in bucket_stage

typedef __bf16 bf16x8 __attribute__((ext_vector_type(8)));
typedef float f32x4 __attribute__((ext_vector_type(4)));

__device__ inline unsigned bf_rne(float x) {      // fp32 -> bf16 bits (RNE)
    unsigned u = __float_as_uint(x);
    u += 0x7fffu + ((u >> 16) & 1u);
    return u >> 16;
}
__device__ inline unsigned bfpack(float x, float y) {
    return bf_rne(x) | (bf_rne(y) << 16);
}
__device__ inline bf16x8 as_bf16x8(uint4 u) {
    bf16x8 v; __builtin_memcpy(&v, &u, 16); return v;
}

// ---------------- bucket-level edge count (LDS-privatized) ----------------
__global__ void bucket_count(const int* __restrict__ col, int* __restrict__ bkcnt, int E) {
    __shared__ int h[256];
    int t = threadIdx.x;
    h[t] = 0;
    __syncthreads();
    int base = blockIdx.x * 4096 + t * 4;
    #pragma unroll
    for (int j = 0; j < 4; ++j) {
        int e = base + j * 1024;
        if (e + 3 < E) {
            int4 c4 = *(const int4*)(col + e);
            atomicAdd(&h[c4.x >> BUCKET_BITS], 1);
            atomicAdd(&h[c4.y >> BUCKET_BITS], 1);
            atomicAdd(&h[c4.z >> BUCKET_BITS], 1);
            atomicAdd(&h[c4.w >> BUCKET_BITS], 1);
        } else if (e < E) {
            for (int q = e; q < E; ++q) atomicAdd(&h[col[q] >> BUCKET_BITS], 1);
        }
    }
    __syncthreads();
    if (h[t]) atomicAdd(&bkcnt[t], h[t]);
}

// ---------------- scan bucket counts -> bucketbase[NB+1] ----------------
__global__ void bucket_scan(const int* __restrict__ bkcnt, int* __restrict__ bucketbase,
                            int NB, int E) {
    __shared__ int tmp[256];
    int t = threadIdx.x;
    int v = (t < NB) ? bkcnt[t] : 0;
    tmp[t] = v;
    __syncthreads();
    for (int off = 1; off < 256; off <<= 1) {
        int u = (t >= off) ? tmp[t - off] : 0;
        __syncthreads();
        tmp[t] += u;
        __syncthreads();
    }
    if (t < NB) bucketbase[t] = tmp[t] - v;
    if (t == 0) bucketbase[NB] = E;
}

// ---------------- bucket-grouped compact append of raw (row,col) ----------------
__global__ void bucket_stage(const int* __restrict__ row, const int* __restrict__ col,
                             const int* __restrict__ bucketbase, int* __restrict__ bcnt2,
                             int2* __restrict__ staged, int E) {
    __shared__ int lcnt[256];
    __shared__ int lbase[256];
    int t = threadIdx.x;
    lcnt[t] = 0;
    __syncthreads();
    int base_e = blockIdx.x * EPB;
    int rr[8], cc[8], pk[8];
    #pragma unroll
    for (int j = 0; j < 8; ++j) {
        int e = base_e + j * 256 + t;
        pk[j] = -1;
        if (e < E) {
            rr[j] = row[e];
            cc[j] = col[e];
            int b = cc[j] >> BUCKET_BITS;
            int off = atomicAdd(&lcnt[b], 1);
            pk[j] = off | (b << 20);
        }
    }
    __syncthreads();
    lbase[t] = lcnt[t] ? atomicAdd(&bcnt2[t], lcnt[t]) : 0;
    __syncthreads();
    #pragma unroll
    for (int j = 0; j < 8; ++j) {
        if (pk[j] >= 0) {
            int b = pk[j] >> 20;
            int off = pk[j] & 0xFFFFF;
            int pos = bucketbase[b] + lbase[b] + off;
            staged[pos] = make_int2(rr[j], cc[j]);
        }
    }
}

// ---------------- per-bucket: node degree hist (LDS) + scan -> rowptr, dinv ----
__global__ void bucket_deg(const int2* __restrict__ staged, const int* __restrict__ bucketbase,
                           int* __restrict__ rowptr, float* __restrict__ dinv, int N, int E) {
    __shared__ int cnt[512];
    int t = threadIdx.x;
    int b = blockIdx.x;
    int beg = bucketbase[b];
    int end = bucketbase[b + 1];
    cnt[t] = 0;
    __syncthreads();
    for (int i = beg + t; i < end; i += 512)
        atomicAdd(&cnt[staged[i].y & 511], 1);
    __syncthreads();
    int v = cnt[t];
    // Hillis-Steele inclusive scan over 512
    for (int off = 1; off < 512; off <<= 1) {
        int u = (t >= off) ? cnt[t - off] : 0;
        __syncthreads();
        cnt[t] += u;
        __syncthreads();
    }
    int node = (b << BUCKET_BITS) + t;
    if (node < N) {
        rowptr[node] = beg + cnt[t] - v;
        dinv[node] = (v > 0) ? (1.0f / sqrtf((float)v)) : 1.0f;
    }
    if (b == 0 && t == 0) rowptr[N] = E;
}

// ---------------- per-bucket final scatter (LDS offsets, zero global atomics) ----
__global__ void bucket_final(const int2* __restrict__ staged, const int* __restrict__ bucketbase,
                             const int* __restrict__ rowptr, const float* __restrict__ dinv,
                             int2* __restrict__ edges, int N) {
    __shared__ int lcnt[512];
    __shared__ int lrow[512];
    __shared__ float ldinv[512];
    int t = threadIdx.x;
    int b = blockIdx.x;
    int beg = bucketbase[b];
    int end = bucketbase[b + 1];
    int node = (b << BUCKET_BITS) + t;
    lcnt[t] = 0;
    lrow[t] = (node < N) ? rowptr[node] : 0;
    ldinv[t] = (node < N) ? dinv[node] : 1.0f;
    __syncthreads();
    for (int i = beg + t; i < end; i += 512) {
        int2 rc = staged[i];
        int cl = rc.y & 511;
        float nrm = dinv[rc.x] * ldinv[cl];
        int pos = lrow[cl] + atomicAdd(&lcnt[cl], 1);
        edges[pos] = make_int2(rc.x, __float_as_int(nrm));
    }
}

// ---------------- W prepack: fp32 W -> (hi,lo) bf16 B-fragments ----------------
// layout: [kslot(16)][ct(4)][lane(64)] -> uint4 (8 bf16, j = k offset)
// lane -> col = ct*16 + (l&15), k = kslot*32 + 8*(l>>4) + j
__global__ void wprep_kernel(const float* __restrict__ W,
                             uint4* __restrict__ whi, uint4* __restrict__ wlo) {
    int tid = blockIdx.x * 256 + threadIdx.x;       // 4096 total
    int kslot = tid >> 8;
    int rem = tid & 255;
    int ct = rem >> 6;
    int l = rem & 63;
    int col = ct * 16 + (l & 15);
    int kbase = kslot * 32 + ((l >> 4) << 3);
    unsigned hbits[8], lbits[8];
    #pragma unroll
    for (int j = 0; j < 8; ++j) {
        float f = W[(size_t)(kbase + j) * C_DIM + col];
        unsigned h = bf_rne(f);
        hbits[j] = h;
        lbits[j] = bf_rne(f - __uint_as_float(h << 16));
    }
    whi[tid] = make_uint4(hbits[0] | (hbits[1] << 16), hbits[2] | (hbits[3] << 16),
                          hbits[4] | (hbits[5] << 16), hbits[6] | (hbits[7] << 16));
    wlo[tid] = make_uint4(lbits[0] | (lbits[1] << 16), lbits[2] | (lbits[3] << 16),
                          lbits[4] | (lbits[5] << 16), lbits[6] | (lbits[7] << 16));
}

// ---------------- split-bf16 MFMA GEMM: h = x @ W + b, emits bf16 hb directly ----
// block = 256 thr (4 waves), tile 128 rows x 64 cols, BK=64, 8 K-chunks.
// error vs fp32: ~2^-18 relative (lo*lo term dropped).
__global__ __launch_bounds__(256) void gemm_mfma(const float4* __restrict__ x4,
                                                 const uint4* __restrict__ whi,
                                                 const uint4* __restrict__ wlo,
                                                 const float* __restrict__ bias,
                                                 uint4* __restrict__ hb, int N) {
    __shared__ float smem[8704];          // 34816 B: staging (32K) / epilogue (34.8K)
    char* ahi = (char*)smem;
    char* alo = ahi + 16384;
    const int t = threadIdx.x;
    const int l = t & 63;
    const int wv = t >> 6;
    const int rowblk = blockIdx.x * 128;

    f32x4 acc[2][4];
    #pragma unroll
    for (int rt = 0; rt < 2; ++rt)
        #pragma unroll
        for (int ct = 0; ct < 4; ++ct) acc[rt][ct] = (f32x4){0.f, 0.f, 0.f, 0.f};

    for (int chunk = 0; chunk < 8; ++chunk) {
        // ---- stage A chunk: fp32 -> (hi,lo) bf16, XOR-swizzled 16B granules ----
        #pragma unroll
        for (int i = 0; i < 4; ++i) {
            int idx = t + 256 * i;            // 1024 granules: 128 rows x 8
            int r = idx >> 3, g = idx & 7;
            int grow = rowblk + r;
            float4 v0 = make_float4(0.f, 0.f, 0.f, 0.f), v1 = v0;
            if (grow < N) {
                const float4* p = x4 + (size_t)grow * (F_IN / 4) + chunk * 16 + g * 2;
                v0 = p[0]; v1 = p[1];
            }
            float f[8] = {v0.x, v0.y, v0.z, v0.w, v1.x, v1.y, v1.z, v1.w};
            unsigned hbits[8], lbits[8];
            #pragma unroll
            for (int j = 0; j < 8; ++j) {
                unsigned h = bf_rne(f[j]);
                hbits[j] = h;
                lbits[j] = bf_rne(f[j] - __uint_as_float(h << 16));
            }
            int off = r * 128 + ((g ^ (r & 7)) << 4);
            *(uint4*)(ahi + off) = make_uint4(hbits[0] | (hbits[1] << 16), hbits[2] | (hbits[3] << 16),
                                              hbits[4] | (hbits[5] << 16), hbits[6] | (hbits[7] << 16));
            *(uint4*)(alo + off) = make_uint4(lbits[0] | (lbits[1] << 16), lbits[2] | (lbits[3] << 16),
                                              lbits[4] | (lbits[5] << 16), lbits[6] | (lbits[7] << 16));
        }
        __syncthreads();
        // ---- A fragments (ds_read_b128, swizzle-matched) ----
        uint4 AH[2][2], AL[2][2];
        #pragma unroll
        for (int rt = 0; rt < 2; ++rt) {
            int r = wv * 32 + rt * 16 + (l & 15);
            int rb = r * 128;
            int rx = r & 7;
            #pragma unroll
            for (int ks = 0; ks < 2; ++ks) {
                int gl = ks * 4 + (l >> 4);
                int off = rb + ((gl ^ rx) << 4);
                AH[rt][ks] = *(const uint4*)(ahi + off);
                AL[rt][ks] = *(const uint4*)(alo + off);
            }
        }
        // ---- B fragments from global (L2-resident, 128 KB) + MFMA ----
        #pragma unroll
        for (int ct = 0; ct < 4; ++ct) {
            int base = (chunk * 8 + ct) * 64 + l;
            uint4 BH0 = whi[base], BH1 = whi[base + 256];
            uint4 BL0 = wlo[base], BL1 = wlo[base + 256];
            #pragma unroll
            for (int rt = 0; rt < 2; ++rt) {
                f32x4 c = acc[rt][ct];
                c = __builtin_amdgcn_mfma_f32_16x16x32_bf16(as_bf16x8(AH[rt][0]), as_bf16x8(BH0), c, 0, 0, 0);
                c = __builtin_amdgcn_mfma_f32_16x16x32_bf16(as_bf16x8(AH[rt][1]), as_bf16x8(BH1), c, 0, 0, 0);
                c = __builtin_amdgcn_mfma_f32_16x16x32_bf16(as_bf16x8(AL[rt][0]), as_bf16x8(BH0), c, 0, 0, 0);
                c = __builtin_amdgcn_mfma_f32_16x16x32_bf16(as_bf16x8(AL[rt][1]), as_bf16x8(BH1), c, 0, 0, 0);
                c = __builtin_amdgcn_mfma_f32_16x16x32_bf16(as_bf16x8(AH[rt][0]), as_bf16x8(BL0), c, 0, 0, 0);
                c = __builtin_amdgcn_mfma_f32_16x16x32_bf16(as_bf16x8(AH[rt][1]), as_bf16x8(BL1), c, 0, 0, 0);
                acc[rt][ct] = c;
            }
        }
        __syncthreads();
    }
    // ---- epilogue: acc -> LDS fp32 (transpose) -> packed bf16 hb ----
    float* ls = smem;                     // stride 68 dwords (16B-aligned rows)
    #pragma unroll
    for (int rt = 0; rt < 2; ++rt) {
        int rbase = wv * 32 + rt * 16 + ((l >> 4) << 2);
        #pragma unroll
        for (int ct = 0; ct < 4; ++ct) {
            int col = ct * 16 + (l & 15);
            float bb = bias[col];
            #pragma unroll
            for (int q = 0; q < 4; ++q)
                ls[(rbase + q) * 68 + col] = acc[rt][ct][q] + bb;
        }
    }
    __syncthreads();
    #pragma unroll
    for (int i = 0; i < 4; ++i) {
        int idx = t + 256 * i;
        int r = idx >> 3, lc = idx & 7;
        int grow = rowblk + r;
        if (grow < N) {
            const float* p = ls + r * 68 + lc * 8;
            float4 A = *(const float4*)p;
            float4 Bv = *(const float4*)(p + 4);
            uint4 nb;
            nb.x = bfpack(A.x, A.y);
            nb.y = bfpack(A.z, A.w);
            nb.z = bfpack(Bv.x, Bv.y);
            nb.w = bfpack(Bv.z, Bv.w);
            hb[(size_t)grow * 8 + lc] = nb;
        }
    }
}

// ---------------- propagation, bf16 state ----------------
// 8 lanes/node, each lane = 8 channels (one uint4 = 8 bf16).
// mode 0: Pout = prop(Hb);  mode 1: Pout = 2*prop(Hb) - unpack(Pold)
// ret == nullptr (lazy path): no ret accumulation; combine_kernel does it later.
__global__ void prop_kernel(const int* __restrict__ rowptr, const int2* __restrict__ edges,
                            const uint4* __restrict__ Hb, const uint4* Pold,
                            uint4* Pout, float4* ret, const float* lap,
                            const float4* mf4, int k, int mode, int N) {
    int gtid = blockIdx.x * blockDim.x + threadIdx.x;
    int node = gtid >> 3;
    int lc = gtid & 7;
    if (node >= N) return;
    int beg = rowptr[node];
    int end = rowptr[node + 1];
    float a0 = 0.f, a1 = 0.f, a2 = 0.f, a3 = 0.f, a4 = 0.f, a5 = 0.f, a6 = 0.f, a7 = 0.f;

#define EDGE_FMA(SRC, WB) do { \
        float w_ = __int_as_float(WB); \
        uint4 u_ = Hb[(size_t)(SRC) * 8 + lc]; \
        a0 = fmaf(w_, __uint_as_float(u_.x << 16), a0); \
        a1 = fmaf(w_, __uint_as_float(u_.x & 0xffff0000u), a1); \
        a2 = fmaf(w_, __uint_as_float(u_.y << 16), a2); \
        a3 = fmaf(w_, __uint_as_float(u_.y & 0xffff0000u), a3); \
        a4 = fmaf(w_, __uint_as_float(u_.z << 16), a4); \
        a5 = fmaf(w_, __uint_as_float(u_.z & 0xffff0000u), a5); \
        a6 = fmaf(w_, __uint_as_float(u_.w << 16), a6); \
        a7 = fmaf(w_, __uint_as_float(u_.w & 0xffff0000u), a7); \
    } while (0)

    int e = beg;
    if ((e & 1) && e < end) {
        int2 d = edges[e];
        EDGE_FMA(d.x, d.y);
        ++e;
    }
    for (; e + 4 <= end; e += 4) {
        int4 p0v = ((const int4*)edges)[e >> 1];
        int4 p1v = ((const int4*)edges)[(e >> 1) + 1];
        EDGE_FMA(p0v.x, p0v.y);
        EDGE_FMA(p0v.z, p0v.w);
        EDGE_FMA(p1v.x, p1v.y);
        EDGE_FMA(p1v.z, p1v.w);
    }
    for (; e < end; ++e) {
        int2 d = edges[e];
        EDGE_FMA(d.x, d.y);
    }
#undef EDGE_FMA

    size_t ib = (size_t)node * 8 + lc;
    float p0, p1, p2, p3, p4, p5, p6, p7;
    if (mode == 0) {
        p0 = a0; p1 = a1; p2 = a2; p3 = a3; p4 = a4; p5 = a5; p6 = a6; p7 = a7;
    } else {
        uint4 ob = Pold[ib];
        p0 = 2.f * a0 - __uint_as_float(ob.x << 16);
        p1 = 2.f * a1 - __uint_as_float(ob.x & 0xffff0000u);
        p2 = 2.f * a2 - __uint_as_float(ob.y << 16);
        p3 = 2.f * a3 - __uint_as_float(ob.y & 0xffff0000u);
        p4 = 2.f * a4 - __uint_as_float(ob.z << 16);
        p5 = 2.f * a5 - __uint_as_float(ob.z & 0xffff0000u);
        p6 = 2.f * a6 - __uint_as_float(ob.w << 16);
        p7 = 2.f * a7 - __uint_as_float(ob.w & 0xffff0000u);
    }
    uint4 nb;
    nb.x = bfpack(p0, p1);
    nb.y = bfpack(p2, p3);
    nb.z = bfpack(p4, p5);
    nb.w = bfpack(p6, p7);
    Pout[ib] = nb;

    if (ret) {   // legacy (small-workspace) path: accumulate into ret per iteration
        float lw = lap[k - 1];
        size_t i16 = (size_t)node * 16 + lc * 2;
        float4 m0 = mf4[k * 16 + lc * 2];
        float4 m1 = mf4[k * 16 + lc * 2 + 1];
        float4 r0 = ret[i16];
        float4 r1 = ret[i16 + 1];
        r0.x = fmaf(lw * m0.x, p0, r0.x);
        r0.y = fmaf(lw * m0.y, p1, r0.y);
        r0.z = fmaf(lw * m0.z, p2, r0.z);
        r0.w = fmaf(lw * m0.w, p3, r0.w);
        r1.x = fmaf(lw * m1.x, p4, r1.x);
        r1.y = fmaf(lw * m1.y, p5, r1.y);
        r1.z = fmaf(lw * m1.z, p6, r1.z);
        r1.w = fmaf(lw * m1.w, p7, r1.w);
        ret[i16] = r0;
        ret[i16 + 1] = r1;
    }
}

// ---------------- fused combine + log-softmax (lazy path) ----------------
// ret[n,c] = logsoftmax_c( h*mf0 + sum_k lap[k-1]*mf_k*P_k )
__global__ void combine_kernel(const uint4* __restrict__ hb, const uint4* __restrict__ Pall,
                               const float* __restrict__ lap, const float* __restrict__ mf,
                               float4* __restrict__ ret, int Kp, int N) {
    __shared__ float smf[1024];
    __shared__ float slap[32];
    int t = threadIdx.x;
    int nmf = (Kp + 1) * 64;
    for (int i = t; i < nmf; i += 256) smf[i] = mf[i];
    if (t < Kp) slap[t] = lap[t];
    __syncthreads();
    int g = blockIdx.x * 256 + t;
    int node = g >> 3, lc = g & 7;
    if (node >= N) return;
    size_t off = (size_t)node * 8 + lc;
    uint4 u = hb[off];
    const float* m0 = smf + lc * 8;
    float a0 = __uint_as_float(u.x << 16) * m0[0];
    float a1 = __uint_as_float(u.x & 0xffff0000u) * m0[1];
    float a2 = __uint_as_float(u.y << 16) * m0[2];
    float a3 = __uint_as_float(u.y & 0xffff0000u) * m0[3];
    float a4 = __uint_as_float(u.z << 16) * m0[4];
    float a5 = __uint_as_float(u.z & 0xffff0000u) * m0[5];
    float a6 = __uint_as_float(u.w << 16) * m0[6];
    float a7 = __uint_as_float(u.w & 0xffff0000u) * m0[7];
    size_t stride = (size_t)N * 8;
    for (int k = 1; k <= Kp; ++k) {
        uint4 p = Pall[(size_t)(k - 1) * stride + off];
        float cw = slap[k - 1];
        const float* mk = smf + k * 64 + lc * 8;
        a0 = fmaf(cw * mk[0], __uint_as_float(p.x << 16), a0);
        a1 = fmaf(cw * mk[1], __uint_as_float(p.x & 0xffff0000u), a1);
        a2 = fmaf(cw * mk[2], __uint_as_float(p.y << 16), a2);
        a3 = fmaf(cw * mk[3], __uint_as_float(p.y & 0xffff0000u), a3);
        a4 = fmaf(cw * mk[4], __uint_as_float(p.z << 16), a4);
        a5 = fmaf(cw * mk[5], __uint_as_float(p.z & 0xffff0000u), a5);
        a6 = fmaf(cw * mk[6], __uint_as_float(p.w << 16), a6);
        a7 = fmaf(cw * mk[7], __uint_as_float(p.w & 0xffff0000u), a7);
    }
    float m = fmaxf(fmaxf(fmaxf(a0, a1), fmaxf(a2, a3)), fmaxf(fmaxf(a4, a5), fmaxf(a6, a7)));
    for (int o = 1; o < 8; o <<= 1) m = fmaxf(m, __shfl_xor(m, o, 8));
    float s = __expf(a0 - m) + __expf(a1 - m) + __expf(a2 - m) + __expf(a3 - m)
            + __expf(a4 - m) + __expf(a5 - m) + __expf(a6 - m) + __expf(a7 - m);
    for (int o = 1; o < 8; o <<= 1) s += __shfl_xor(s, o, 8);
    float lg = logf(s) + m;
    ret[(size_t)node * 16 + lc * 2]     = make_float4(a0 - lg, a1 - lg, a2 - lg, a3 - lg);
    ret[(size_t)node * 16 + lc * 2 + 1] = make_float4(a4 - lg, a5 - lg, a6 - lg, a7 - lg);
}

// ---------------- legacy: init ret with P0 term ----------------
__global__ void p0ret_kernel(const uint4* __restrict__ hb, float4* __restrict__ ret,
                             const float4* __restrict__ mf4, int N) {
    int g = blockIdx.x * 256 + threadIdx.x;
    int node = g >> 3, lc = g & 7;
    if (node >= N) return;
    uint4 u = hb[(size_t)node * 8 + lc];
    float4 m0 = mf4[lc * 2], m1 = mf4[lc * 2 + 1];
    float4 r0 = make_float4(__uint_as_float(u.x << 16) * m0.x,
                            __uint_as_float(u.x & 0xffff0000u) * m0.y,
                            __uint_as_float(u.y << 16) * m0.z,
                            __uint_as_float(u.y & 0xffff0000u) * m0.w);
    float4 r1 = make_float4(__uint_as_float(u.z << 16) * m1.x,
                            __uint_as_float(u.z & 0xffff0000u) * m1.y,
                            __uint_as_float(u.w << 16) * m1.z,
                            __uint_as_float(u.w & 0xffff0000u) * m1.w);
    ret[(size_t)node * 16 + lc * 2] = r0;
    ret[(size_t)node * 16 + lc * 2 + 1] = r1;
}

// ---------------- log softmax (legacy path only) ----------------
__global__ void lsm_kernel(float* __restrict__ ret, int N) {
    int wid = (blockIdx.x * blockDim.x + threadIdx.x) >> 6;
    int c = threadIdx.x & 63;
    if (wid >= N) return;
    size_t idx = (size_t)wid * C_DIM + c;
    float v = ret[idx];
    float m = v;
    for (int off = 32; off; off >>= 1) m = fmaxf(m, __shfl_xor(m, off, 64));
    float ex = __expf(v - m);
    float s = ex;
    for (int off = 32; off; off >>= 1) s += __shfl_xor(s, off, 64);
    ret[idx] = (v - m) - logf(s);
}

extern "C" void kernel_launch(void* const* d_in, const int* in_sizes, int n_in,
                              void* d_out, int out_size, void* d_ws, size_t ws_size,
                              hipStream_t stream) {
    const float* x   = (const float*)d_in[0];
    const int*   ei  = (const int*)d_in[1];
    const float* W   = (const float*)d_in[2];
    const float* b   = (const float*)d_in[3];
    const float* lap = (const float*)d_in[4];
    const float* mf  = (const float*)d_in[5];
    float* ret = (float*)d_out;

    const int C = in_sizes[3];            // 64
    const int FIN = in_sizes[2] / C;      // 512
    const int N = in_sizes[0] / FIN;      // 100000
    const int E = in_sizes[1] / 2;        // 3200000
    const int K = in_sizes[4] - 1;        // 10
    const int* rowi = ei;
    const int* coli = ei + E;
    const int NB = (N + (1 << BUCKET_BITS) - 1) >> BUCKET_BITS;   // 196, must be <=256

    char* w = (char*)d_ws;
    auto alloc = [&](size_t bytes) {
        void* p = (void*)w;
        w += (bytes + 255) & ~(size_t)255;
        return p;
    };
    int*   rowptr = (int*)alloc((size_t)(N + 1) * 4);
    float* dinv   = (float*)alloc((size_t)N * 4);
    int*   bkcnt  = (int*)alloc(1024);
    int*   bucketbase = (int*)alloc(4096);
    int*   bcnt2  = (int*)alloc(1024);
    uint4* whi    = (uint4*)alloc(65536);                 // 16 kslot x 4 ct x 64 lane x 16B
    uint4* wlo    = (uint4*)alloc(65536);
    int2*  edges  = (int2*)alloc((size_t)E * 8);
    uint4* hb     = (uint4*)alloc((size_t)N * 128);       // bf16 h (P0), 12.8 MB

    const size_t slab = (size_t)N * 128;                  // one bf16 [N,64] buffer
    size_t used = (size_t)(w - (char*)d_ws);
    bool lazy = (ws_size > used) && ((ws_size - used) >= (size_t)K * slab);

    uint4* Pall = nullptr;
    uint4* pb = nullptr;
    int2* staged;
    if (lazy) {
        Pall = (uint4*)alloc((size_t)K * slab);           // P1..PK, 128 MB
        staged = (int2*)Pall;                             // dead until props start (E*8 <= K*slab)
    } else {
        pb = (uint4*)alloc(slab);
        staged = (int2*)hb;                               // hb+pb contiguous = E*8 bytes
    }

    hipMemsetAsync(bkcnt, 0, 1024, stream);
    hipMemsetAsync(bcnt2, 0, 1024, stream);

    bucket_count<<<(E + 4095) / 4096, 256, 0, stream>>>(coli, bkcnt, E);
    bucket_scan<<<1, 256, 0, stream>>>(bkcnt, bucketbase, NB, E);
    bucket_stage<<<(E + EPB - 1) / EPB, 256, 0, stream>>>(rowi, coli, bucketbase, bcnt2,
                                                          staged, E);
    bucket_deg<<<NB, 512, 0, stream>>>(staged, bucketbase, rowptr, dinv, N, E);
    bucket_final<<<NB, 512, 0, stream>>>(staged, bucketbase, rowptr, dinv, edges, N);

    wprep_kernel<<<16, 256, 0, stream>>>(W, whi, wlo);
    gemm_mfma<<<(N + 127) / 128, 256, 0, stream>>>((const float4*)x, whi, wlo, b, hb, N);

    int pgrid = (N * 8 + 255) / 256;
    if (lazy) {
        // P1 = prop(P0)
        prop_kernel<<<pgrid, 256, 0, stream>>>(rowptr, edges, hb, Pall, Pall,
                                               nullptr, nullptr, nullptr, 1, 0, N);
        for (int k2 = 2; k2 <= K; ++k2) {
            const uint4* src  = Pall + (size_t)(k2 - 2) * N * 8;
            const uint4* pold = (k2 == 2) ? hb : Pall + (size_t)(k2 - 3) * N * 8;
            uint4* out = Pall + (size_t)(k2 - 1) * N * 8;
            prop_kernel<<<pgrid, 256, 0, stream>>>(rowptr, edges, src, pold, out,
                                                   nullptr, nullptr, nullptr, k2, 1, N);
        }
        combine_kernel<<<pgrid, 256, 0, stream>>>(hb, Pall, lap, mf, (float4*)ret, K, N);
    } else {
        p0ret_kernel<<<pgrid, 256, 0, stream>>>(hb, (float4*)ret, (const float4*)mf, N);
        prop_kernel<<<pgrid, 256, 0, stream>>>(rowptr, edges, hb, pb, pb, (float4*)ret,
                                               lap, (const float4*)mf, 1, 0, N);
        uint4* gat = pb;
        uint4* st  = hb;
        for (int k2 = 2; k2 <= K; ++k2) {
            prop_kernel<<<pgrid, 256, 0, stream>>>(rowptr, edges, gat, st, st, (float4*)ret,
                                                   lap, (const float4*)mf, k2, 1, N);
            uint4* t2 = gat; gat = st; st = t2;
        }
        lsm_kernel<<<((size_t)N * 64 + 255) / 256, 256, 0, stream>>>(ret, N);
    }
}

// Round 3
// 999.352 us; speedup vs baseline: 1.3468x; 1.0409x over previous
//
#include <hip/hip_runtime.h>

#define F_IN 512
#define C_DIM 64
#define BUCKET_BITS 9          // 512 nodes per bucket
#define EPB 2048               // edges per block in bucket_stage

typedef __bf16 bf16x8 __attribute__((ext_vector_type(8)));
typedef float f32x4 __attribute__((ext_vector_type(4)));

__device__ inline unsigned bf_rne(float x) {      // fp32 -> bf16 bits (RNE)
    unsigned u = __float_as_uint(x);
    u += 0x7fffu + ((u >> 16) & 1u);
    return u >> 16;
}
__device__ inline unsigned bfpack(float x, float y) {
    return bf_rne(x) | (bf_rne(y) << 16);
}
__device__ inline bf16x8 as_bf16x8(uint4 u) {
    bf16x8 v; __builtin_memcpy(&v, &u, 16); return v;
}

// ---------------- bucket-level edge count (LDS-privatized) ----------------
__global__ void bucket_count(const int* __restrict__ col, int* __restrict__ bkcnt, int E) {
    __shared__ int h[256];
    int t = threadIdx.x;
    h[t] = 0;
    __syncthreads();
    int base = blockIdx.x * 4096 + t * 4;
    #pragma unroll
    for (int j = 0; j < 4; ++j) {
        int e = base + j * 1024;
        if (e + 3 < E) {
            int4 c4 = *(const int4*)(col + e);
            atomicAdd(&h[c4.x >> BUCKET_BITS], 1);
            atomicAdd(&h[c4.y >> BUCKET_BITS], 1);
            atomicAdd(&h[c4.z >> BUCKET_BITS], 1);
            atomicAdd(&h[c4.w >> BUCKET_BITS], 1);
        } else if (e < E) {
            for (int q = e; q < E; ++q) atomicAdd(&h[col[q] >> BUCKET_BITS], 1);
        }
    }
    __syncthreads();
    if (h[t]) atomicAdd(&bkcnt[t], h[t]);
}

// ---------------- scan bucket counts -> bucketbase[NB+1] ----------------
__global__ void bucket_scan(const int* __restrict__ bkcnt, int* __restrict__ bucketbase,
                            int NB, int E) {
    __shared__ int tmp[256];
    int t = threadIdx.x;
    int v = (t < NB) ? bkcnt[t] : 0;
    tmp[t] = v;
    __syncthreads();
    for (int off = 1; off < 256; off <<= 1) {
        int u = (t >= off) ? tmp[t - off] : 0;
        __syncthreads();
        tmp[t] += u;
        __syncthreads();
    }
    if (t < NB) bucketbase[t] = tmp[t] - v;
    if (t == 0) bucketbase[NB] = E;
}

// ---------------- bucket-grouped compact append of raw (row,col) ----------------
__global__ void bucket_stage(const int* __restrict__ row, const int* __restrict__ col,
                             const int* __restrict__ bucketbase, int* __restrict__ bcnt2,
                             int2* __restrict__ staged, int E) {
    __shared__ int lcnt[256];
    __shared__ int lbase[256];
    int t = threadIdx.x;
    lcnt[t] = 0;
    __syncthreads();
    int base_e = blockIdx.x * EPB;
    int rr[8], cc[8], pk[8];
    #pragma unroll
    for (int j = 0; j < 8; ++j) {
        int e = base_e + j * 256 + t;
        pk[j] = -1;
        if (e < E) {
            rr[j] = row[e];
            cc[j] = col[e];
            int b = cc[j] >> BUCKET_BITS;
            int off = atomicAdd(&lcnt[b], 1);
            pk[j] = off | (b << 20);
        }
    }
    __syncthreads();
    lbase[t] = lcnt[t] ? atomicAdd(&bcnt2[t], lcnt[t]) : 0;
    __syncthreads();
    #pragma unroll
    for (int j = 0; j < 8; ++j) {
        if (pk[j] >= 0) {
            int b = pk[j] >> 20;
            int off = pk[j] & 0xFFFFF;
            int pos = bucketbase[b] + lbase[b] + off;
            staged[pos] = make_int2(rr[j], cc[j]);
        }
    }
}

// ---------------- per-bucket: node degree hist (LDS) + scan -> rowptr, dinv ----
__global__ void bucket_deg(const int2* __restrict__ staged, const int* __restrict__ bucketbase,
                           int* __restrict__ rowptr, float* __restrict__ dinv, int N, int E) {
    __shared__ int cnt[512];
    int t = threadIdx.x;
    int b = blockIdx.x;
    int beg = bucketbase[b];
    int end = bucketbase[b + 1];
    cnt[t] = 0;
    __syncthreads();
    for (int i = beg + t; i < end; i += 512)
        atomicAdd(&cnt[staged[i].y & 511], 1);
    __syncthreads();
    int v = cnt[t];
    // Hillis-Steele inclusive scan over 512
    for (int off = 1; off < 512; off <<= 1) {
        int u = (t >= off) ? cnt[t - off] : 0;
        __syncthreads();
        cnt[t] += u;
        __syncthreads();
    }
    int node = (b << BUCKET_BITS) + t;
    if (node < N) {
        rowptr[node] = beg + cnt[t] - v;
        dinv[node] = (v > 0) ? (1.0f / sqrtf((float)v)) : 1.0f;
    }
    if (b == 0 && t == 0) rowptr[N] = E;
}

// ---------------- per-bucket final scatter (LDS offsets, zero global atomics) ----
__global__ void bucket_final(const int2* __restrict__ staged, const int* __restrict__ bucketbase,
                             const int* __restrict__ rowptr, const float* __restrict__ dinv,
                             int2* __restrict__ edges, int N) {
    __shared__ int lcnt[512];
    __shared__ int lrow[512];
    __shared__ float ldinv[512];
    int t = threadIdx.x;
    int b = blockIdx.x;
    int beg = bucketbase[b];
    int end = bucketbase[b + 1];
    int node = (b << BUCKET_BITS) + t;
    lcnt[t] = 0;
    lrow[t] = (node < N) ? rowptr[node] : 0;
    ldinv[t] = (node < N) ? dinv[node] : 1.0f;
    __syncthreads();
    for (int i = beg + t; i < end; i += 512) {
        int2 rc = staged[i];
        int cl = rc.y & 511;
        float nrm = dinv[rc.x] * ldinv[cl];
        int pos = lrow[cl] + atomicAdd(&lcnt[cl], 1);
        edges[pos] = make_int2(rc.x, __float_as_int(nrm));
    }
}

// ---------------- W prepack: fp32 W -> (hi,lo) bf16 B-fragments ----------------
__global__ void wprep_kernel(const float* __restrict__ W,
                             uint4* __restrict__ whi, uint4* __restrict__ wlo) {
    int tid = blockIdx.x * 256 + threadIdx.x;       // 4096 total
    int kslot = tid >> 8;
    int rem = tid & 255;
    int ct = rem >> 6;
    int l = rem & 63;
    int col = ct * 16 + (l & 15);
    int kbase = kslot * 32 + ((l >> 4) << 3);
    unsigned hbits[8], lbits[8];
    #pragma unroll
    for (int j = 0; j < 8; ++j) {
        float f = W[(size_t)(kbase + j) * C_DIM + col];
        unsigned h = bf_rne(f);
        hbits[j] = h;
        lbits[j] = bf_rne(f - __uint_as_float(h << 16));
    }
    whi[tid] = make_uint4(hbits[0] | (hbits[1] << 16), hbits[2] | (hbits[3] << 16),
                          hbits[4] | (hbits[5] << 16), hbits[6] | (hbits[7] << 16));
    wlo[tid] = make_uint4(lbits[0] | (lbits[1] << 16), lbits[2] | (lbits[3] << 16),
                          lbits[4] | (lbits[5] << 16), lbits[6] | (lbits[7] << 16));
}

// ---------------- split-bf16 MFMA GEMM: h = x @ W + b, emits bf16 hb directly ----
__global__ __launch_bounds__(256) void gemm_mfma(const float4* __restrict__ x4,
                                                 const uint4* __restrict__ whi,
                                                 const uint4* __restrict__ wlo,
                                                 const float* __restrict__ bias,
                                                 uint4* __restrict__ hb, int N) {
    __shared__ float smem[8704];          // 34816 B: staging (32K) / epilogue (34.8K)
    char* ahi = (char*)smem;
    char* alo = ahi + 16384;
    const int t = threadIdx.x;
    const int l = t & 63;
    const int wv = t >> 6;
    const int rowblk = blockIdx.x * 128;

    f32x4 acc[2][4];
    #pragma unroll
    for (int rt = 0; rt < 2; ++rt)
        #pragma unroll
        for (int ct = 0; ct < 4; ++ct) acc[rt][ct] = (f32x4){0.f, 0.f, 0.f, 0.f};

    for (int chunk = 0; chunk < 8; ++chunk) {
        // ---- stage A chunk: fp32 -> (hi,lo) bf16, XOR-swizzled 16B granules ----
        #pragma unroll
        for (int i = 0; i < 4; ++i) {
            int idx = t + 256 * i;            // 1024 granules: 128 rows x 8
            int r = idx >> 3, g = idx & 7;
            int grow = rowblk + r;
            float4 v0 = make_float4(0.f, 0.f, 0.f, 0.f), v1 = v0;
            if (grow < N) {
                const float4* p = x4 + (size_t)grow * (F_IN / 4) + chunk * 16 + g * 2;
                v0 = p[0]; v1 = p[1];
            }
            float f[8] = {v0.x, v0.y, v0.z, v0.w, v1.x, v1.y, v1.z, v1.w};
            unsigned hbits[8], lbits[8];
            #pragma unroll
            for (int j = 0; j < 8; ++j) {
                unsigned h = bf_rne(f[j]);
                hbits[j] = h;
                lbits[j] = bf_rne(f[j] - __uint_as_float(h << 16));
            }
            int off = r * 128 + ((g ^ (r & 7)) << 4);
            *(uint4*)(ahi + off) = make_uint4(hbits[0] | (hbits[1] << 16), hbits[2] | (hbits[3] << 16),
                                              hbits[4] | (hbits[5] << 16), hbits[6] | (hbits[7] << 16));
            *(uint4*)(alo + off) = make_uint4(lbits[0] | (lbits[1] << 16), lbits[2] | (lbits[3] << 16),
                                              lbits[4] | (lbits[5] << 16), lbits[6] | (lbits[7] << 16));
        }
        __syncthreads();
        // ---- A fragments (ds_read_b128, swizzle-matched) ----
        uint4 AH[2][2], AL[2][2];
        #pragma unroll
        for (int rt = 0; rt < 2; ++rt) {
            int r = wv * 32 + rt * 16 + (l & 15);
            int rb = r * 128;
            int rx = r & 7;
            #pragma unroll
            for (int ks = 0; ks < 2; ++ks) {
                int gl = ks * 4 + (l >> 4);
                int off = rb + ((gl ^ rx) << 4);
                AH[rt][ks] = *(const uint4*)(ahi + off);
                AL[rt][ks] = *(const uint4*)(alo + off);
            }
        }
        // ---- B fragments from global (L2-resident, 128 KB) + MFMA ----
        #pragma unroll
        for (int ct = 0; ct < 4; ++ct) {
            int base = (chunk * 8 + ct) * 64 + l;
            uint4 BH0 = whi[base], BH1 = whi[base + 256];
            uint4 BL0 = wlo[base], BL1 = wlo[base + 256];
            #pragma unroll
            for (int rt = 0; rt < 2; ++rt) {
                f32x4 c = acc[rt][ct];
                c = __builtin_amdgcn_mfma_f32_16x16x32_bf16(as_bf16x8(AH[rt][0]), as_bf16x8(BH0), c, 0, 0, 0);
                c = __builtin_amdgcn_mfma_f32_16x16x32_bf16(as_bf16x8(AH[rt][1]), as_bf16x8(BH1), c, 0, 0, 0);
                c = __builtin_amdgcn_mfma_f32_16x16x32_bf16(as_bf16x8(AL[rt][0]), as_bf16x8(BH0), c, 0, 0, 0);
                c = __builtin_amdgcn_mfma_f32_16x16x32_bf16(as_bf16x8(AL[rt][1]), as_bf16x8(BH1), c, 0, 0, 0);
                c = __builtin_amdgcn_mfma_f32_16x16x32_bf16(as_bf16x8(AH[rt][0]), as_bf16x8(BL0), c, 0, 0, 0);
                c = __builtin_amdgcn_mfma_f32_16x16x32_bf16(as_bf16x8(AH[rt][1]), as_bf16x8(BL1), c, 0, 0, 0);
                acc[rt][ct] = c;
            }
        }
        __syncthreads();
    }
    // ---- epilogue: acc -> LDS fp32 (transpose) -> packed bf16 hb ----
    float* ls = smem;                     // stride 68 dwords (16B-aligned rows)
    #pragma unroll
    for (int rt = 0; rt < 2; ++rt) {
        int rbase = wv * 32 + rt * 16 + ((l >> 4) << 2);
        #pragma unroll
        for (int ct = 0; ct < 4; ++ct) {
            int col = ct * 16 + (l & 15);
            float bb = bias[col];
            #pragma unroll
            for (int q = 0; q < 4; ++q)
                ls[(rbase + q) * 68 + col] = acc[rt][ct][q] + bb;
        }
    }
    __syncthreads();
    #pragma unroll
    for (int i = 0; i < 4; ++i) {
        int idx = t + 256 * i;
        int r = idx >> 3, lc = idx & 7;
        int grow = rowblk + r;
        if (grow < N) {
            const float* p = ls + r * 68 + lc * 8;
            float4 A = *(const float4*)p;
            float4 Bv = *(const float4*)(p + 4);
            uint4 nb;
            nb.x = bfpack(A.x, A.y);
            nb.y = bfpack(A.z, A.w);
            nb.z = bfpack(Bv.x, Bv.y);
            nb.w = bfpack(Bv.z, Bv.w);
            hb[(size_t)grow * 8 + lc] = nb;
        }
    }
}

// ---------------- propagation v2: one wave per node ----------------
// 64 lanes = 8 edge-slots (g) x 8 channel-lanes (lc). Per 32-edge chunk:
// 4 coalesced edge-load steps, 4 independent 8-line gathers, FMAs, then
// shfl_xor butterfly reduce over edge-slots. No intra-wave degree divergence.
__global__ __launch_bounds__(256) void prop2_kernel(const int* __restrict__ rowptr,
                                                    const int2* __restrict__ edges,
                                                    const uint4* __restrict__ Hb,
                                                    const uint4* __restrict__ Pold,
                                                    uint4* __restrict__ Pout,
                                                    int mode, int N) {
    int wid = (blockIdx.x * 256 + threadIdx.x) >> 6;   // node id, one wave per node
    if (wid >= N) return;
    int l = threadIdx.x & 63;
    int g = l >> 3;        // edge slot 0..7
    int lc = l & 7;        // channel quad 0..7
    int beg = rowptr[wid];
    int count = rowptr[wid + 1] - beg;

    float a0 = 0.f, a1 = 0.f, a2 = 0.f, a3 = 0.f, a4 = 0.f, a5 = 0.f, a6 = 0.f, a7 = 0.f;

    for (int base = 0; base < count; base += 32) {
        // 4 steps x 8 slots = 32 edges; padded steps use edge 0 with w=0.
        int2 d[4];
        float wv[4];
        #pragma unroll
        for (int s = 0; s < 4; ++s) {
            int eidx = base + s * 8 + g;
            bool v = eidx < count;
            d[s] = edges[beg + (v ? eidx : 0)];
            wv[s] = v ? __int_as_float(d[s].y) : 0.f;
        }
        uint4 u[4];
        #pragma unroll
        for (int s = 0; s < 4; ++s)
            u[s] = Hb[(size_t)d[s].x * 8 + lc];
        #pragma unroll
        for (int s = 0; s < 4; ++s) {
            float w_ = wv[s];
            uint4 u_ = u[s];
            a0 = fmaf(w_, __uint_as_float(u_.x << 16), a0);
            a1 = fmaf(w_, __uint_as_float(u_.x & 0xffff0000u), a1);
            a2 = fmaf(w_, __uint_as_float(u_.y << 16), a2);
            a3 = fmaf(w_, __uint_as_float(u_.y & 0xffff0000u), a3);
            a4 = fmaf(w_, __uint_as_float(u_.z << 16), a4);
            a5 = fmaf(w_, __uint_as_float(u_.z & 0xffff0000u), a5);
            a6 = fmaf(w_, __uint_as_float(u_.w << 16), a6);
            a7 = fmaf(w_, __uint_as_float(u_.w & 0xffff0000u), a7);
        }
    }

    // reduce across the 8 edge slots (lane bits 3..5)
    #pragma unroll
    for (int off = 8; off <= 32; off <<= 1) {
        a0 += __shfl_xor(a0, off, 64);
        a1 += __shfl_xor(a1, off, 64);
        a2 += __shfl_xor(a2, off, 64);
        a3 += __shfl_xor(a3, off, 64);
        a4 += __shfl_xor(a4, off, 64);
        a5 += __shfl_xor(a5, off, 64);
        a6 += __shfl_xor(a6, off, 64);
        a7 += __shfl_xor(a7, off, 64);
    }

    if (l < 8) {
        size_t ib = (size_t)wid * 8 + lc;
        float p0, p1, p2, p3, p4, p5, p6, p7;
        if (mode == 0) {
            p0 = a0; p1 = a1; p2 = a2; p3 = a3; p4 = a4; p5 = a5; p6 = a6; p7 = a7;
        } else {
            uint4 ob = Pold[ib];
            p0 = 2.f * a0 - __uint_as_float(ob.x << 16);
            p1 = 2.f * a1 - __uint_as_float(ob.x & 0xffff0000u);
            p2 = 2.f * a2 - __uint_as_float(ob.y << 16);
            p3 = 2.f * a3 - __uint_as_float(ob.y & 0xffff0000u);
            p4 = 2.f * a4 - __uint_as_float(ob.z << 16);
            p5 = 2.f * a5 - __uint_as_float(ob.z & 0xffff0000u);
            p6 = 2.f * a6 - __uint_as_float(ob.w << 16);
            p7 = 2.f * a7 - __uint_as_float(ob.w & 0xffff0000u);
        }
        uint4 nb;
        nb.x = bfpack(p0, p1);
        nb.y = bfpack(p2, p3);
        nb.z = bfpack(p4, p5);
        nb.w = bfpack(p6, p7);
        Pout[ib] = nb;
    }
}

// ---------------- legacy propagation (small-workspace fallback) ----------------
__global__ void prop_kernel(const int* __restrict__ rowptr, const int2* __restrict__ edges,
                            const uint4* __restrict__ Hb, const uint4* Pold,
                            uint4* Pout, float4* ret, const float* lap,
                            const float4* mf4, int k, int mode, int N) {
    int gtid = blockIdx.x * blockDim.x + threadIdx.x;
    int node = gtid >> 3;
    int lc = gtid & 7;
    if (node >= N) return;
    int beg = rowptr[node];
    int end = rowptr[node + 1];
    float a0 = 0.f, a1 = 0.f, a2 = 0.f, a3 = 0.f, a4 = 0.f, a5 = 0.f, a6 = 0.f, a7 = 0.f;

#define EDGE_FMA(SRC, WB) do { \
        float w_ = __int_as_float(WB); \
        uint4 u_ = Hb[(size_t)(SRC) * 8 + lc]; \
        a0 = fmaf(w_, __uint_as_float(u_.x << 16), a0); \
        a1 = fmaf(w_, __uint_as_float(u_.x & 0xffff0000u), a1); \
        a2 = fmaf(w_, __uint_as_float(u_.y << 16), a2); \
        a3 = fmaf(w_, __uint_as_float(u_.y & 0xffff0000u), a3); \
        a4 = fmaf(w_, __uint_as_float(u_.z << 16), a4); \
        a5 = fmaf(w_, __uint_as_float(u_.z & 0xffff0000u), a5); \
        a6 = fmaf(w_, __uint_as_float(u_.w << 16), a6); \
        a7 = fmaf(w_, __uint_as_float(u_.w & 0xffff0000u), a7); \
    } while (0)

    for (int e = beg; e < end; ++e) {
        int2 dd = edges[e];
        EDGE_FMA(dd.x, dd.y);
    }
#undef EDGE_FMA

    size_t ib = (size_t)node * 8 + lc;
    float p0, p1, p2, p3, p4, p5, p6, p7;
    if (mode == 0) {
        p0 = a0; p1 = a1; p2 = a2; p3 = a3; p4 = a4; p5 = a5; p6 = a6; p7 = a7;
    } else {
        uint4 ob = Pold[ib];
        p0 = 2.f * a0 - __uint_as_float(ob.x << 16);
        p1 = 2.f * a1 - __uint_as_float(ob.x & 0xffff0000u);
        p2 = 2.f * a2 - __uint_as_float(ob.y << 16);
        p3 = 2.f * a3 - __uint_as_float(ob.y & 0xffff0000u);
        p4 = 2.f * a4 - __uint_as_float(ob.z << 16);
        p5 = 2.f * a5 - __uint_as_float(ob.z & 0xffff0000u);
        p6 = 2.f * a6 - __uint_as_float(ob.w << 16);
        p7 = 2.f * a7 - __uint_as_float(ob.w & 0xffff0000u);
    }
    uint4 nb;
    nb.x = bfpack(p0, p1);
    nb.y = bfpack(p2, p3);
    nb.z = bfpack(p4, p5);
    nb.w = bfpack(p6, p7);
    Pout[ib] = nb;

    if (ret) {
        float lw = lap[k - 1];
        size_t i16 = (size_t)node * 16 + lc * 2;
        float4 m0 = mf4[k * 16 + lc * 2];
        float4 m1 = mf4[k * 16 + lc * 2 + 1];
        float4 r0 = ret[i16];
        float4 r1 = ret[i16 + 1];
        r0.x = fmaf(lw * m0.x, p0, r0.x);
        r0.y = fmaf(lw * m0.y, p1, r0.y);
        r0.z = fmaf(lw * m0.z, p2, r0.z);
        r0.w = fmaf(lw * m0.w, p3, r0.w);
        r1.x = fmaf(lw * m1.x, p4, r1.x);
        r1.y = fmaf(lw * m1.y, p5, r1.y);
        r1.z = fmaf(lw * m1.z, p6, r1.z);
        r1.w = fmaf(lw * m1.w, p7, r1.w);
        ret[i16] = r0;
        ret[i16 + 1] = r1;
    }
}

// ---------------- fused combine + log-softmax (lazy path) ----------------
__global__ void combine_kernel(const uint4* __restrict__ hb, const uint4* __restrict__ Pall,
                               const float* __restrict__ lap, const float* __restrict__ mf,
                               float4* __restrict__ ret, int Kp, int N) {
    __shared__ float smf[1024];
    __shared__ float slap[32];
    int t = threadIdx.x;
    int nmf = (Kp + 1) * 64;
    for (int i = t; i < nmf; i += 256) smf[i] = mf[i];
    if (t < Kp) slap[t] = lap[t];
    __syncthreads();
    int g = blockIdx.x * 256 + t;
    int node = g >> 3, lc = g & 7;
    if (node >= N) return;
    size_t off = (size_t)node * 8 + lc;
    uint4 u = hb[off];
    const float* m0 = smf + lc * 8;
    float a0 = __uint_as_float(u.x << 16) * m0[0];
    float a1 = __uint_as_float(u.x & 0xffff0000u) * m0[1];
    float a2 = __uint_as_float(u.y << 16) * m0[2];
    float a3 = __uint_as_float(u.y & 0xffff0000u) * m0[3];
    float a4 = __uint_as_float(u.z << 16) * m0[4];
    float a5 = __uint_as_float(u.z & 0xffff0000u) * m0[5];
    float a6 = __uint_as_float(u.w << 16) * m0[6];
    float a7 = __uint_as_float(u.w & 0xffff0000u) * m0[7];
    size_t stride = (size_t)N * 8;
    for (int k = 1; k <= Kp; ++k) {
        uint4 p = Pall[(size_t)(k - 1) * stride + off];
        float cw = slap[k - 1];
        const float* mk = smf + k * 64 + lc * 8;
        a0 = fmaf(cw * mk[0], __uint_as_float(p.x << 16), a0);
        a1 = fmaf(cw * mk[1], __uint_as_float(p.x & 0xffff0000u), a1);
        a2 = fmaf(cw * mk[2], __uint_as_float(p.y << 16), a2);
        a3 = fmaf(cw * mk[3], __uint_as_float(p.y & 0xffff0000u), a3);
        a4 = fmaf(cw * mk[4], __uint_as_float(p.z << 16), a4);
        a5 = fmaf(cw * mk[5], __uint_as_float(p.z & 0xffff0000u), a5);
        a6 = fmaf(cw * mk[6], __uint_as_float(p.w << 16), a6);
        a7 = fmaf(cw * mk[7], __uint_as_float(p.w & 0xffff0000u), a7);
    }
    float m = fmaxf(fmaxf(fmaxf(a0, a1), fmaxf(a2, a3)), fmaxf(fmaxf(a4, a5), fmaxf(a6, a7)));
    for (int o = 1; o < 8; o <<= 1) m = fmaxf(m, __shfl_xor(m, o, 8));
    float s = __expf(a0 - m) + __expf(a1 - m) + __expf(a2 - m) + __expf(a3 - m)
            + __expf(a4 - m) + __expf(a5 - m) + __expf(a6 - m) + __expf(a7 - m);
    for (int o = 1; o < 8; o <<= 1) s += __shfl_xor(s, o, 8);
    float lg = logf(s) + m;
    ret[(size_t)node * 16 + lc * 2]     = make_float4(a0 - lg, a1 - lg, a2 - lg, a3 - lg);
    ret[(size_t)node * 16 + lc * 2 + 1] = make_float4(a4 - lg, a5 - lg, a6 - lg, a7 - lg);
}

// ---------------- legacy: init ret with P0 term ----------------
__global__ void p0ret_kernel(const uint4* __restrict__ hb, float4* __restrict__ ret,
                             const float4* __restrict__ mf4, int N) {
    int g = blockIdx.x * 256 + threadIdx.x;
    int node = g >> 3, lc = g & 7;
    if (node >= N) return;
    uint4 u = hb[(size_t)node * 8 + lc];
    float4 m0 = mf4[lc * 2], m1 = mf4[lc * 2 + 1];
    float4 r0 = make_float4(__uint_as_float(u.x << 16) * m0.x,
                            __uint_as_float(u.x & 0xffff0000u) * m0.y,
                            __uint_as_float(u.y << 16) * m0.z,
                            __uint_as_float(u.y & 0xffff0000u) * m0.w);
    float4 r1 = make_float4(__uint_as_float(u.z << 16) * m1.x,
                            __uint_as_float(u.z & 0xffff0000u) * m1.y,
                            __uint_as_float(u.w << 16) * m1.z,
                            __uint_as_float(u.w & 0xffff0000u) * m1.w);
    ret[(size_t)node * 16 + lc * 2] = r0;
    ret[(size_t)node * 16 + lc * 2 + 1] = r1;
}

// ---------------- log softmax (legacy path only) ----------------
__global__ void lsm_kernel(float* __restrict__ ret, int N) {
    int wid = (blockIdx.x * blockDim.x + threadIdx.x) >> 6;
    int c = threadIdx.x & 63;
    if (wid >= N) return;
    size_t idx = (size_t)wid * C_DIM + c;
    float v = ret[idx];
    float m = v;
    for (int off = 32; off; off >>= 1) m = fmaxf(m, __shfl_xor(m, off, 64));
    float ex = __expf(v - m);
    float s = ex;
    for (int off = 32; off; off >>= 1) s += __shfl_xor(s, off, 64);
    ret[idx] = (v - m) - logf(s);
}

extern "C" void kernel_launch(void* const* d_in, const int* in_sizes, int n_in,
                              void* d_out, int out_size, void* d_ws, size_t ws_size,
                              hipStream_t stream) {
    const float* x   = (const float*)d_in[0];
    const int*   ei  = (const int*)d_in[1];
    const float* W   = (const float*)d_in[2];
    const float* b   = (const float*)d_in[3];
    const float* lap = (const float*)d_in[4];
    const float* mf  = (const float*)d_in[5];
    float* ret = (float*)d_out;

    const int C = in_sizes[3];            // 64
    const int FIN = in_sizes[2] / C;      // 512
    const int N = in_sizes[0] / FIN;      // 100000
    const int E = in_sizes[1] / 2;        // 3200000
    const int K = in_sizes[4] - 1;        // 10
    const int* rowi = ei;
    const int* coli = ei + E;
    const int NB = (N + (1 << BUCKET_BITS) - 1) >> BUCKET_BITS;   // 196, must be <=256

    char* w = (char*)d_ws;
    auto alloc = [&](size_t bytes) {
        void* p = (void*)w;
        w += (bytes + 255) & ~(size_t)255;
        return p;
    };
    int*   rowptr = (int*)alloc((size_t)(N + 1) * 4);
    float* dinv   = (float*)alloc((size_t)N * 4);
    int*   bkcnt  = (int*)alloc(1024);
    int*   bucketbase = (int*)alloc(4096);
    int*   bcnt2  = (int*)alloc(1024);
    uint4* whi    = (uint4*)alloc(65536);                 // 16 kslot x 4 ct x 64 lane x 16B
    uint4* wlo    = (uint4*)alloc(65536);
    int2*  edges  = (int2*)alloc((size_t)E * 8);
    uint4* hb     = (uint4*)alloc((size_t)N * 128);       // bf16 h (P0), 12.8 MB

    const size_t slab = (size_t)N * 128;                  // one bf16 [N,64] buffer
    size_t used = (size_t)(w - (char*)d_ws);
    bool lazy = (ws_size > used) && ((ws_size - used) >= (size_t)K * slab);

    uint4* Pall = nullptr;
    uint4* pb = nullptr;
    int2* staged;
    if (lazy) {
        Pall = (uint4*)alloc((size_t)K * slab);           // P1..PK, 128 MB
        staged = (int2*)Pall;                             // dead until props start (E*8 <= K*slab)
    } else {
        pb = (uint4*)alloc(slab);
        staged = (int2*)hb;                               // hb+pb contiguous = E*8 bytes
    }

    hipMemsetAsync(bkcnt, 0, 1024, stream);
    hipMemsetAsync(bcnt2, 0, 1024, stream);

    bucket_count<<<(E + 4095) / 4096, 256, 0, stream>>>(coli, bkcnt, E);
    bucket_scan<<<1, 256, 0, stream>>>(bkcnt, bucketbase, NB, E);
    bucket_stage<<<(E + EPB - 1) / EPB, 256, 0, stream>>>(rowi, coli, bucketbase, bcnt2,
                                                          staged, E);
    bucket_deg<<<NB, 512, 0, stream>>>(staged, bucketbase, rowptr, dinv, N, E);
    bucket_final<<<NB, 512, 0, stream>>>(staged, bucketbase, rowptr, dinv, edges, N);

    wprep_kernel<<<16, 256, 0, stream>>>(W, whi, wlo);
    gemm_mfma<<<(N + 127) / 128, 256, 0, stream>>>((const float4*)x, whi, wlo, b, hb, N);

    if (lazy) {
        int pgrid2 = (N + 3) / 4;                         // one wave per node
        // P1 = prop(P0)
        prop2_kernel<<<pgrid2, 256, 0, stream>>>(rowptr, edges, hb, Pall, Pall, 0, N);
        for (int k2 = 2; k2 <= K; ++k2) {
            const uint4* src  = Pall + (size_t)(k2 - 2) * N * 8;
            const uint4* pold = (k2 == 2) ? hb : Pall + (size_t)(k2 - 3) * N * 8;
            uint4* out = Pall + (size_t)(k2 - 1) * N * 8;
            prop2_kernel<<<pgrid2, 256, 0, stream>>>(rowptr, edges, src, pold, out, 1, N);
        }
        int pgrid = (N * 8 + 255) / 256;
        combine_kernel<<<pgrid, 256, 0, stream>>>(hb, Pall, lap, mf, (float4*)ret, K, N);
    } else {
        int pgrid = (N * 8 + 255) / 256;
        p0ret_kernel<<<pgrid, 256, 0, stream>>>(hb, (float4*)ret, (const float4*)mf, N);
        prop_kernel<<<pgrid, 256, 0, stream>>>(rowptr, edges, hb, pb, pb, (float4*)ret,
                                               lap, (const float4*)mf, 1, 0, N);
        uint4* gat = pb;
        uint4* st  = hb;
        for (int k2 = 2; k2 <= K; ++k2) {
            prop_kernel<<<pgrid, 256, 0, stream>>>(rowptr, edges, gat, st, st, (float4*)ret,
                                                   lap, (const float4*)mf, k2, 1, N);
            uint4* t2 = gat; gat = st; st = t2;
        }
        lsm_kernel<<<((size_t)N * 64 + 255) / 256, 256, 0, stream>>>(ret, N);
    }
}